// Round 1
// baseline (1661.751 us; speedup 1.0000x reference)
//
#include <hip/hip_runtime.h>

#define N_NODES 100000
#define E_EDGES 3200000
#define F_IN    512
#define C_OUT   64
#define NB      1563     // buckets: node >> 6 (64 nodes per bucket)
#define CAP     2560     // bucket capacity (mean 2048, sigma ~45 -> 11 sigma)
#define TILE    16384    // edges per block in P2
#define NTILE   196      // ceil(E / TILE)

typedef __bf16 bf16x8 __attribute__((ext_vector_type(8)));
typedef float  f32x4  __attribute__((ext_vector_type(4)));
typedef float  f32x2  __attribute__((ext_vector_type(2)));

// fp32 -> bf16 (round-to-nearest-even), bit-level
static __device__ __forceinline__ unsigned short f2bf(float f) {
    unsigned int u = __float_as_uint(f);
    u = (u + 0x7FFFu + ((u >> 16) & 1u)) >> 16;
    return (unsigned short)u;
}
// bf16 bits -> fp32 (exact)
static __device__ __forceinline__ float bf2f(unsigned short b) {
    return __uint_as_float(((unsigned int)b) << 16);
}
// fp32 -> fp8 e4m3 (OCP on gfx950), single byte via HW convert
static __device__ __forceinline__ unsigned char f32_to_fp8(float v) {
    return (unsigned char)(__builtin_amdgcn_cvt_pk_fp8_f32(v, v, 0, false) & 0xFF);
}
// 2 packed fp8 -> 2 fp32 via HW convert (same HW format as encode)
static __device__ __forceinline__ f32x2 fp8x2_to_f32(unsigned short u) {
    return __builtin_amdgcn_cvt_pk_f32_fp8((int)(unsigned int)u, false);
}

// ---------------------------------------------------------------------------
// zero: out-degree array + bucket cursors
// ---------------------------------------------------------------------------
__global__ __launch_bounds__(512) void zero_kernel(int* __restrict__ deg_src,
                                                   int* __restrict__ cursor_d) {
    int i = blockIdx.x * 512 + threadIdx.x;
    if (i < N_NODES) deg_src[i] = 0;
    if (i < NB) cursor_d[i] = 0;
}

// ---------------------------------------------------------------------------
// P2: two-pass dst-partition into fixed-capacity bucket regions + global
// out-degree count.
// Pass A: LDS histogram of dst>>6; global atomicAdd on deg_src (random over
//         100K ints -> low contention, L2-resident).
// Reserve: one global atomic per (block,bucket).
// Pass B: re-read (L2-hot) and write packed runs:
//   tmp[b*CAP..] : u32 (dst&63)<<24 | src
// ---------------------------------------------------------------------------
__global__ __launch_bounds__(512) void p2_part(const int* __restrict__ src,
                                               const int* __restrict__ dst,
                                               int* __restrict__ cursor_d,
                                               int* __restrict__ deg_src,
                                               unsigned int* __restrict__ tmp) {
    __shared__ int cd[NB];
    __shared__ int bd[NB];
    int t = threadIdx.x;
    for (int j = t; j < NB; j += 512) cd[j] = 0;
    __syncthreads();
    int tb = blockIdx.x * TILE;
    // --- pass A: count ---
    #pragma unroll 4
    for (int i = 0; i < 32; ++i) {
        int e = tb + i * 512 + t;
        if (e < E_EDGES) {
            atomicAdd(&cd[dst[e] >> 6], 1);
            atomicAdd(&deg_src[src[e]], 1);
        }
    }
    __syncthreads();
    // --- reserve contiguous runs ---
    for (int j = t; j < NB; j += 512) {
        int c = cd[j];
        bd[j] = j * CAP + (c ? atomicAdd(&cursor_d[j], c) : 0);
        cd[j] = 0;
    }
    __syncthreads();
    // --- pass B: write ---
    #pragma unroll 4
    for (int i = 0; i < 32; ++i) {
        int e = tb + i * 512 + t;
        if (e < E_EDGES) {
            int s = src[e], d = dst[e];
            int db = d >> 6;
            int p = atomicAdd(&cd[db], 1);
            tmp[bd[db] + p] = ((unsigned int)(d & 63) << 24) | (unsigned int)s;
        }
    }
}

// ---------------------------------------------------------------------------
// GEMM (bf16 MFMA): writes h0b (bf16, for teleport term) AND h8 = fp8(h0).
// (norm_src is now applied per-edge in agg_kernel, so GEMM has no graph dep.)
// ---------------------------------------------------------------------------
__global__ __launch_bounds__(256) void gemm_kernel(const float* __restrict__ A,
                                                   const float* __restrict__ W,
                                                   const float* __restrict__ bias,
                                                   unsigned short* __restrict__ h0b,
                                                   unsigned char* __restrict__ h8) {
    __shared__ unsigned short Wl[64 * 520];   // 66560 B

    const int tid  = threadIdx.x;
    const int w    = tid >> 6;
    const int lane = tid & 63;
    const int cl   = lane & 15;
    const int quad = lane >> 4;
    const int row0 = blockIdx.x * 64;

    #pragma unroll 8
    for (int j = 0; j < 32; ++j) {
        int e4 = (j * 256 + tid) * 4;
        float4 wv = *reinterpret_cast<const float4*>(&W[e4]);
        int c = e4 >> 9;
        int k = e4 & 511;
        unsigned short* d = &Wl[c * 520 + k];
        d[0] = f2bf(wv.x); d[1] = f2bf(wv.y); d[2] = f2bf(wv.z); d[3] = f2bf(wv.w);
    }
    __syncthreads();

    int arow = row0 + w * 16 + cl;
    if (arow >= N_NODES) arow = N_NODES - 1;
    const float* aptr = A + (size_t)arow * F_IN + quad * 8;

    f32x4 acc0 = {0.f, 0.f, 0.f, 0.f};
    f32x4 acc1 = {0.f, 0.f, 0.f, 0.f};
    f32x4 acc2 = {0.f, 0.f, 0.f, 0.f};
    f32x4 acc3 = {0.f, 0.f, 0.f, 0.f};

    for (int k0 = 0; k0 < F_IN; k0 += 32) {
        float4 p = *reinterpret_cast<const float4*>(aptr + k0);
        float4 q = *reinterpret_cast<const float4*>(aptr + k0 + 4);
        bf16x8 af;
        af[0] = (__bf16)p.x; af[1] = (__bf16)p.y; af[2] = (__bf16)p.z; af[3] = (__bf16)p.w;
        af[4] = (__bf16)q.x; af[5] = (__bf16)q.y; af[6] = (__bf16)q.z; af[7] = (__bf16)q.w;

        const unsigned short* wb = &Wl[k0 + quad * 8];
        bf16x8 b0 = *reinterpret_cast<const bf16x8*>(wb + (cl +  0) * 520);
        bf16x8 b1 = *reinterpret_cast<const bf16x8*>(wb + (cl + 16) * 520);
        bf16x8 b2 = *reinterpret_cast<const bf16x8*>(wb + (cl + 32) * 520);
        bf16x8 b3 = *reinterpret_cast<const bf16x8*>(wb + (cl + 48) * 520);

        acc0 = __builtin_amdgcn_mfma_f32_16x16x32_bf16(af, b0, acc0, 0, 0, 0);
        acc1 = __builtin_amdgcn_mfma_f32_16x16x32_bf16(af, b1, acc1, 0, 0, 0);
        acc2 = __builtin_amdgcn_mfma_f32_16x16x32_bf16(af, b2, acc2, 0, 0, 0);
        acc3 = __builtin_amdgcn_mfma_f32_16x16x32_bf16(af, b3, acc3, 0, 0, 0);
    }

    float bias0 = bias[cl +  0];
    float bias1 = bias[cl + 16];
    float bias2 = bias[cl + 32];
    float bias3 = bias[cl + 48];
    #pragma unroll
    for (int r = 0; r < 4; ++r) {
        int row = row0 + w * 16 + quad * 4 + r;
        if (row < N_NODES) {
            float v0 = acc0[r] + bias0;
            float v1 = acc1[r] + bias1;
            float v2 = acc2[r] + bias2;
            float v3 = acc3[r] + bias3;
            unsigned short* o = &h0b[(size_t)row * C_OUT + cl];
            o[ 0] = f2bf(v0);
            o[16] = f2bf(v1);
            o[32] = f2bf(v2);
            o[48] = f2bf(v3);
            unsigned char* o8 = &h8[(size_t)row * C_OUT + cl];
            o8[ 0] = f32_to_fp8(v0);
            o8[16] = f32_to_fp8(v1);
            o8[32] = f32_to_fp8(v2);
            o8[48] = f32_to_fp8(v3);
        }
    }
}

// ---------------------------------------------------------------------------
// agg: block b owns the 64 nodes [64b, 64b+64). Reads its bucket's packed
// edge run from tmp, scatter-adds fp8-decoded h8 rows into a 16KB LDS fp32
// accumulator (ds_add_f32; bank = lane%32 -> free 2-way aliasing), then
// writes out = 0.8*norm_dst*acc + 0.2*h0. Replaces p3_build + CSR gather:
// no edge_src round-trip, no per-node serial tails, no degree imbalance.
// wave-per-edge, 8 edges in flight per wave; 8 blocks/CU (16.9KB LDS).
// ---------------------------------------------------------------------------
__global__ __launch_bounds__(256, 8) void agg_kernel(const unsigned int* __restrict__ tmp,
                                                     const int* __restrict__ cursor_d,
                                                     const int* __restrict__ deg_src,
                                                     const unsigned char* __restrict__ h8,
                                                     const unsigned short* __restrict__ h0b,
                                                     float* __restrict__ out) {
    __shared__ float acc[64 * 64];   // 16 KB
    __shared__ int   cnt[64];
    __shared__ float ndl[64];

    int t = threadIdx.x;
    int b = blockIdx.x;

    for (int q = t; q < 64 * 64 / 4; q += 256)
        reinterpret_cast<f32x4*>(acc)[q] = (f32x4){0.f, 0.f, 0.f, 0.f};
    if (t < 64) cnt[t] = 0;
    __syncthreads();

    int bbase = b * CAP;
    int bend  = bbase + cursor_d[b];
    int nE    = bend - bbase;

    // in-degree histogram (for norm_dst) — 64 lanes/op, ~8 iters
    for (int e = bbase + t; e < bend; e += 256)
        atomicAdd(&cnt[tmp[e] >> 24], 1);

    // edge scatter-add: each wave takes chunks of 8 edges, stride 32
    int wid  = t >> 6;
    int lane = t & 63;
    const unsigned int* te = tmp + bbase;
    int i = wid * 8;
    for (; i + 8 <= nE; i += 32) {
        unsigned int v[8];
        #pragma unroll
        for (int k = 0; k < 8; ++k) v[k] = te[i + k];
        int dg[8];
        int c[8];
        #pragma unroll
        for (int k = 0; k < 8; ++k) {
            unsigned int s = v[k] & 0xFFFFFFu;
            dg[k] = deg_src[s];
            c[k]  = h8[s * 64u + (unsigned int)lane];
        }
        #pragma unroll
        for (int k = 0; k < 8; ++k) {
            float f = fp8x2_to_f32((unsigned short)c[k])[0] * rsqrtf((float)dg[k]);
            atomicAdd(&acc[(int)((v[k] >> 24) << 6) + lane], f);
        }
    }
    // tail: at most one wave owns the final partial chunk (<8 edges)
    for (; i < nE; ++i) {
        unsigned int v = te[i];
        unsigned int s = v & 0xFFFFFFu;
        float f = fp8x2_to_f32((unsigned short)h8[s * 64u + (unsigned int)lane])[0]
                * rsqrtf((float)deg_src[s]);
        atomicAdd(&acc[(int)((v >> 24) << 6) + lane], f);
    }

    __syncthreads();
    if (t < 64) {
        int dg = cnt[t];
        ndl[t] = rsqrtf((float)(dg < 1 ? 1 : dg));   // clamp: dg==0 -> nd=1 (acc=0)
    }
    __syncthreads();

    const unsigned int* h32 = reinterpret_cast<const unsigned int*>(h0b); // row stride 32
    for (int p = t; p < 64 * 32; p += 256) {
        int nl = p >> 5;
        int c2 = p & 31;
        int node = (b << 6) + nl;
        if (node < N_NODES) {
            unsigned int hu = h32[(size_t)node * 32 + c2];
            float nd = ndl[nl];
            float2 r;
            r.x = 0.8f * nd * acc[(nl << 6) + c2 * 2]     + 0.2f * bf2f((unsigned short)hu);
            r.y = 0.8f * nd * acc[(nl << 6) + c2 * 2 + 1] + 0.2f * bf2f((unsigned short)(hu >> 16));
            *reinterpret_cast<float2*>(&out[(size_t)node * C_OUT + c2 * 2]) = r;
        }
    }
}

// ---------------------------------------------------------------------------
extern "C" void kernel_launch(void* const* d_in, const int* in_sizes, int n_in,
                              void* d_out, int out_size, void* d_ws, size_t ws_size,
                              hipStream_t stream) {
    const float* in_feat = (const float*)d_in[0];   // [N, 512]
    const float* W       = (const float*)d_in[1];   // [64, 512]
    const float* bias    = (const float*)d_in[2];   // [64]
    const int*   src     = (const int*)d_in[3];     // [E]
    const int*   dst     = (const int*)d_in[4];     // [E]
    float* out = (float*)d_out;                     // [N, 64]

    // workspace layout (no aliasing; ~36MB of ~800MB):
    char* p = (char*)d_ws;
    unsigned short* h0b = (unsigned short*)p;  p += (size_t)N_NODES * C_OUT * 2;   // 12.8MB
    unsigned char*  h8  = (unsigned char*)p;   p += (size_t)N_NODES * C_OUT;       // 6.4MB
    unsigned int*   tmp = (unsigned int*)p;    p += (size_t)NB * CAP * 4;          // 16MB
    int*   deg_src  = (int*)p;                 p += (size_t)N_NODES * 4;           // 0.4MB
    int*   cursor_d = (int*)p;

    zero_kernel<<<(N_NODES + 511) / 512, 512, 0, stream>>>(deg_src, cursor_d);
    p2_part<<<NTILE, 512, 0, stream>>>(src, dst, cursor_d, deg_src, tmp);
    gemm_kernel<<<(N_NODES + 63) / 64, 256, 0, stream>>>(in_feat, W, bias, h0b, h8);
    agg_kernel<<<NB, 256, 0, stream>>>(tmp, cursor_d, deg_src, h8, h0b, out);
}

// Round 2
// 501.192 us; speedup vs baseline: 3.3156x; 3.3156x over previous
//
#include <hip/hip_runtime.h>

#define N_NODES 100000
#define E_EDGES 3200000
#define F_IN    512
#define C_OUT   64
#define NB      391      // coarse buckets: node >> 8 (256 nodes per bucket)
#define CAP     10240    // bucket capacity (mean 8184, sigma 90 -> 22 sigma)
#define TILE    16384    // edges per block in P2
#define NTILE   196      // ceil(E / TILE)

typedef __bf16 bf16x8 __attribute__((ext_vector_type(8)));
typedef float  f32x4  __attribute__((ext_vector_type(4)));
typedef float  f32x2  __attribute__((ext_vector_type(2)));

// fp32 -> bf16 (round-to-nearest-even), bit-level
static __device__ __forceinline__ unsigned short f2bf(float f) {
    unsigned int u = __float_as_uint(f);
    u = (u + 0x7FFFu + ((u >> 16) & 1u)) >> 16;
    return (unsigned short)u;
}
// bf16 bits -> fp32 (exact)
static __device__ __forceinline__ float bf2f(unsigned short b) {
    return __uint_as_float(((unsigned int)b) << 16);
}
// fp32 -> fp8 e4m3 (OCP on gfx950), single byte via HW convert
static __device__ __forceinline__ unsigned char f32_to_fp8(float v) {
    return (unsigned char)(__builtin_amdgcn_cvt_pk_fp8_f32(v, v, 0, false) & 0xFF);
}
// 2 packed fp8 -> 2 fp32 via HW convert (same HW format as encode)
static __device__ __forceinline__ f32x2 fp8x2_to_f32(unsigned short u) {
    return __builtin_amdgcn_cvt_pk_f32_fp8((int)(unsigned int)u, false);
}

// ---------------------------------------------------------------------------
// zero: bucket cursors only
// ---------------------------------------------------------------------------
__global__ __launch_bounds__(512) void zero_kernel(int* __restrict__ cursor_d,
                                                   int* __restrict__ cursor_s) {
    int idx = threadIdx.x;
    if (idx < NB) { cursor_d[idx] = 0; cursor_s[idx] = 0; }
}

// ---------------------------------------------------------------------------
// P2: two-pass dual partition into fixed-capacity bucket regions.
// Pass A: LDS histograms of dst>>8 / src>>8. Reserve: one global atomic per
// (block,bucket). Pass B: re-read (L2-hot) and write packed runs.
//   tmp [b*CAP..] : u32 (dst&255)<<24 | src      (dst-partitioned)
//   tmp2[b*CAP..] : u8  src&255                   (src-partitioned)
// ---------------------------------------------------------------------------
__global__ __launch_bounds__(512) void p2_part(const int* __restrict__ src,
                                               const int* __restrict__ dst,
                                               int* __restrict__ cursor_d,
                                               int* __restrict__ cursor_s,
                                               unsigned int* __restrict__ tmp,
                                               unsigned char* __restrict__ tmp2) {
    __shared__ int cd[NB];
    __shared__ int bd[NB];
    __shared__ int cs[NB];
    __shared__ int bs[NB];
    int t = threadIdx.x;
    for (int j = t; j < NB; j += 512) { cd[j] = 0; cs[j] = 0; }
    __syncthreads();
    int tb = blockIdx.x * TILE;
    // --- pass A: count ---
    #pragma unroll 4
    for (int i = 0; i < 32; ++i) {
        int e = tb + i * 512 + t;
        if (e < E_EDGES) {
            atomicAdd(&cd[dst[e] >> 8], 1);
            atomicAdd(&cs[src[e] >> 8], 1);
        }
    }
    __syncthreads();
    // --- reserve contiguous runs ---
    for (int j = t; j < NB; j += 512) {
        int c = cd[j];
        bd[j] = j * CAP + (c ? atomicAdd(&cursor_d[j], c) : 0);
        cd[j] = 0;
        c = cs[j];
        bs[j] = j * CAP + (c ? atomicAdd(&cursor_s[j], c) : 0);
        cs[j] = 0;
    }
    __syncthreads();
    // --- pass B: write ---
    #pragma unroll 4
    for (int i = 0; i < 32; ++i) {
        int e = tb + i * 512 + t;
        if (e < E_EDGES) {
            int s = src[e], d = dst[e];
            int db = d >> 8;
            int p = atomicAdd(&cd[db], 1);
            tmp[bd[db] + p] = ((unsigned int)(d & 255) << 24) | (unsigned int)s;
            int sb = s >> 8;
            int q = atomicAdd(&cs[sb], 1);
            tmp2[bs[sb] + q] = (unsigned char)(s & 255);
        }
    }
}

// ---------------------------------------------------------------------------
// P3: block b owns nodes [256b, 256b+256). Builds dst-CSR (row_beg/row_end,
// edge_src, norm_dst) and out-degree histogram from tmp2 -> norm_src.
// All heavy writes land inside one 40KB bucket region (L2-local).
// ---------------------------------------------------------------------------
__global__ __launch_bounds__(256) void p3_build(const unsigned int* __restrict__ tmp,
                                                const unsigned char* __restrict__ tmp2,
                                                const int* __restrict__ cursor_d,
                                                const int* __restrict__ cursor_s,
                                                int* __restrict__ row_beg,
                                                int* __restrict__ row_end,
                                                int* __restrict__ edge_src,
                                                float* __restrict__ norm_src,
                                                float* __restrict__ norm_dst) {
    __shared__ int cnt[256];
    __shared__ int off[256];
    __shared__ int lc[256];
    __shared__ int s[256];
    __shared__ int cnt2[256];
    int t = threadIdx.x;
    int b = blockIdx.x;
    int bbase = b * CAP;
    int bend  = bbase + cursor_d[b];
    int sbase = b * CAP;
    int send  = sbase + cursor_s[b];
    cnt[t] = 0;
    lc[t] = 0;
    cnt2[t] = 0;
    __syncthreads();
    for (int e = bbase + t; e < bend; e += 256)
        atomicAdd(&cnt[tmp[e] >> 24], 1);
    for (int e = sbase + t; e < send; e += 256)
        atomicAdd(&cnt2[tmp2[e]], 1);
    __syncthreads();
    int vv = cnt[t];
    s[t] = vv;
    __syncthreads();
    #pragma unroll
    for (int o = 1; o < 256; o <<= 1) {
        int add = (t >= o) ? s[t - o] : 0;
        __syncthreads();
        s[t] += add;
        __syncthreads();
    }
    off[t] = s[t] - vv;
    __syncthreads();
    int node = b * 256 + t;
    if (node < N_NODES) {
        row_beg[node] = bbase + off[t];
        row_end[node] = bbase + off[t] + vv;
        norm_dst[node] = rsqrtf((float)(vv < 1 ? 1 : vv));
        int dg = cnt2[t];
        norm_src[node] = rsqrtf((float)(dg < 1 ? 1 : dg));
    }
    for (int e = bbase + t; e < bend; e += 256) {
        unsigned int v = tmp[e];
        int dl = v >> 24;
        int p = atomicAdd(&lc[dl], 1);
        edge_src[bbase + off[dl] + p] = (int)(v & 0x00FFFFFFu);
    }
}

// ---------------------------------------------------------------------------
// GEMM (bf16 MFMA), 256 rows/block: each of 4 waves owns 4 M-tiles (16 rows
// each) and reuses every B-fragment 4x -> 16 MFMA per K-step per wave, W
// staging amortized 4x (391 blocks instead of 1563). Writes h0b (bf16, for
// teleport term) AND h8[n][c] = fp8(h0[n][c] * norm_src[n]).
// ---------------------------------------------------------------------------
__global__ __launch_bounds__(256) void gemm_kernel(const float* __restrict__ A,
                                                   const float* __restrict__ W,
                                                   const float* __restrict__ bias,
                                                   const float* __restrict__ norm_src,
                                                   unsigned short* __restrict__ h0b,
                                                   unsigned char* __restrict__ h8) {
    __shared__ unsigned short Wl[64 * 520];   // 66560 B

    const int tid  = threadIdx.x;
    const int w    = tid >> 6;
    const int lane = tid & 63;
    const int cl   = lane & 15;
    const int quad = lane >> 4;
    const int row0 = blockIdx.x * 256;

    #pragma unroll 8
    for (int j = 0; j < 32; ++j) {
        int e4 = (j * 256 + tid) * 4;
        float4 wv = *reinterpret_cast<const float4*>(&W[e4]);
        int c = e4 >> 9;
        int k = e4 & 511;
        unsigned short* d = &Wl[c * 520 + k];
        d[0] = f2bf(wv.x); d[1] = f2bf(wv.y); d[2] = f2bf(wv.z); d[3] = f2bf(wv.w);
    }
    __syncthreads();

    const float* aptr[4];
    #pragma unroll
    for (int mt = 0; mt < 4; ++mt) {
        int arow = row0 + mt * 64 + w * 16 + cl;
        if (arow >= N_NODES) arow = N_NODES - 1;
        aptr[mt] = A + (size_t)arow * F_IN + quad * 8;
    }

    f32x4 acc0[4], acc1[4], acc2[4], acc3[4];
    #pragma unroll
    for (int mt = 0; mt < 4; ++mt) {
        acc0[mt] = (f32x4){0.f, 0.f, 0.f, 0.f};
        acc1[mt] = (f32x4){0.f, 0.f, 0.f, 0.f};
        acc2[mt] = (f32x4){0.f, 0.f, 0.f, 0.f};
        acc3[mt] = (f32x4){0.f, 0.f, 0.f, 0.f};
    }

    for (int k0 = 0; k0 < F_IN; k0 += 32) {
        bf16x8 af[4];
        #pragma unroll
        for (int mt = 0; mt < 4; ++mt) {
            float4 p = *reinterpret_cast<const float4*>(aptr[mt] + k0);
            float4 q = *reinterpret_cast<const float4*>(aptr[mt] + k0 + 4);
            af[mt][0] = (__bf16)p.x; af[mt][1] = (__bf16)p.y;
            af[mt][2] = (__bf16)p.z; af[mt][3] = (__bf16)p.w;
            af[mt][4] = (__bf16)q.x; af[mt][5] = (__bf16)q.y;
            af[mt][6] = (__bf16)q.z; af[mt][7] = (__bf16)q.w;
        }

        const unsigned short* wb = &Wl[k0 + quad * 8];
        bf16x8 b0 = *reinterpret_cast<const bf16x8*>(wb + (cl +  0) * 520);
        bf16x8 b1 = *reinterpret_cast<const bf16x8*>(wb + (cl + 16) * 520);
        bf16x8 b2 = *reinterpret_cast<const bf16x8*>(wb + (cl + 32) * 520);
        bf16x8 b3 = *reinterpret_cast<const bf16x8*>(wb + (cl + 48) * 520);

        #pragma unroll
        for (int mt = 0; mt < 4; ++mt) {
            acc0[mt] = __builtin_amdgcn_mfma_f32_16x16x32_bf16(af[mt], b0, acc0[mt], 0, 0, 0);
            acc1[mt] = __builtin_amdgcn_mfma_f32_16x16x32_bf16(af[mt], b1, acc1[mt], 0, 0, 0);
            acc2[mt] = __builtin_amdgcn_mfma_f32_16x16x32_bf16(af[mt], b2, acc2[mt], 0, 0, 0);
            acc3[mt] = __builtin_amdgcn_mfma_f32_16x16x32_bf16(af[mt], b3, acc3[mt], 0, 0, 0);
        }
    }

    float bias0 = bias[cl +  0];
    float bias1 = bias[cl + 16];
    float bias2 = bias[cl + 32];
    float bias3 = bias[cl + 48];
    #pragma unroll
    for (int mt = 0; mt < 4; ++mt) {
        #pragma unroll
        for (int r = 0; r < 4; ++r) {
            int row = row0 + mt * 64 + w * 16 + quad * 4 + r;
            if (row < N_NODES) {
                float v0 = acc0[mt][r] + bias0;
                float v1 = acc1[mt][r] + bias1;
                float v2 = acc2[mt][r] + bias2;
                float v3 = acc3[mt][r] + bias3;
                unsigned short* o = &h0b[(size_t)row * C_OUT + cl];
                o[ 0] = f2bf(v0);
                o[16] = f2bf(v1);
                o[32] = f2bf(v2);
                o[48] = f2bf(v3);
                float ns = norm_src[row];
                unsigned char* o8 = &h8[(size_t)row * C_OUT + cl];
                o8[ 0] = f32_to_fp8(v0 * ns);
                o8[16] = f32_to_fp8(v1 * ns);
                o8[32] = f32_to_fp8(v2 * ns);
                o8[48] = f32_to_fp8(v3 * ns);
            }
        }
    }
}

// ---------------------------------------------------------------------------
// gather: one wave64 per dst node. 32 lanes x 2 channels; 2 edge slots
// (half = lane>>5); 8-deep unroll per slot = 16 edges in flight.
// h8 rows are fp8 with norm_src pre-folded: one 64B line per edge, pure adds.
// ---------------------------------------------------------------------------
__global__ __launch_bounds__(256) void gather_kernel(const int* __restrict__ row_beg,
                                                     const int* __restrict__ row_end,
                                                     const int* __restrict__ edge_src,
                                                     const unsigned char* __restrict__ h8,
                                                     const unsigned short* __restrict__ h0b,
                                                     const float* __restrict__ norm_dst,
                                                     float* __restrict__ out) {
    int node = blockIdx.x * 4 + (threadIdx.x >> 6);
    int lane = threadIdx.x & 63;
    if (node >= N_NODES) return;
    int half = lane >> 5;          // edge slot 0/1
    int c2   = lane & 31;          // channel pair 2*c2, 2*c2+1

    const unsigned short* h8p = reinterpret_cast<const unsigned short*>(h8); // row stride 32
    const unsigned int*   h32 = reinterpret_cast<const unsigned int*>(h0b);  // row stride 32

    int beg = row_beg[node];
    int end = row_end[node];
    float ax = 0.0f, ay = 0.0f;

    int base = beg;
    for (; base + 16 <= end; base += 16) {
        int e0 = base + half;
        int s0 = edge_src[e0 +  0];
        int s1 = edge_src[e0 +  2];
        int s2 = edge_src[e0 +  4];
        int s3 = edge_src[e0 +  6];
        int s4 = edge_src[e0 +  8];
        int s5 = edge_src[e0 + 10];
        int s6 = edge_src[e0 + 12];
        int s7 = edge_src[e0 + 14];
        unsigned short u0 = h8p[s0 * 32 + c2];
        unsigned short u1 = h8p[s1 * 32 + c2];
        unsigned short u2 = h8p[s2 * 32 + c2];
        unsigned short u3 = h8p[s3 * 32 + c2];
        unsigned short u4 = h8p[s4 * 32 + c2];
        unsigned short u5 = h8p[s5 * 32 + c2];
        unsigned short u6 = h8p[s6 * 32 + c2];
        unsigned short u7 = h8p[s7 * 32 + c2];
        f32x2 f0 = fp8x2_to_f32(u0);
        f32x2 f1 = fp8x2_to_f32(u1);
        f32x2 f2 = fp8x2_to_f32(u2);
        f32x2 f3 = fp8x2_to_f32(u3);
        f32x2 f4 = fp8x2_to_f32(u4);
        f32x2 f5 = fp8x2_to_f32(u5);
        f32x2 f6 = fp8x2_to_f32(u6);
        f32x2 f7 = fp8x2_to_f32(u7);
        ax += (f0[0] + f1[0]) + (f2[0] + f3[0]) + (f4[0] + f5[0]) + (f6[0] + f7[0]);
        ay += (f0[1] + f1[1]) + (f2[1] + f3[1]) + (f4[1] + f5[1]) + (f6[1] + f7[1]);
    }
    for (int e = base + half; e < end; e += 2) {
        int s = edge_src[e];
        f32x2 f = fp8x2_to_f32(h8p[s * 32 + c2]);
        ax += f[0];
        ay += f[1];
    }

    ax += __shfl(ax, lane ^ 32, 64);
    ay += __shfl(ay, lane ^ 32, 64);

    if (half == 0) {
        unsigned int hu = h32[node * 32 + c2];
        float nd = norm_dst[node];
        float2 r;
        r.x = 0.8f * nd * ax + 0.2f * bf2f((unsigned short)hu);
        r.y = 0.8f * nd * ay + 0.2f * bf2f((unsigned short)(hu >> 16));
        *reinterpret_cast<float2*>(&out[node * C_OUT + c2 * 2]) = r;
    }
}

// ---------------------------------------------------------------------------
extern "C" void kernel_launch(void* const* d_in, const int* in_sizes, int n_in,
                              void* d_out, int out_size, void* d_ws, size_t ws_size,
                              hipStream_t stream) {
    const float* in_feat = (const float*)d_in[0];   // [N, 512]
    const float* W       = (const float*)d_in[1];   // [64, 512]
    const float* bias    = (const float*)d_in[2];   // [64]
    const int*   src     = (const int*)d_in[3];     // [E]
    const int*   dst     = (const int*)d_in[4];     // [E]
    float* out = (float*)d_out;                     // [N, 64]

    // workspace layout (no aliasing; ws is ~800MB, we use ~57MB):
    char* p = (char*)d_ws;
    unsigned short* h0b = (unsigned short*)p;  p += (size_t)N_NODES * C_OUT * 2;   // 12.8MB
    unsigned char*  h8  = (unsigned char*)p;   p += (size_t)N_NODES * C_OUT;       // 6.4MB
    unsigned int*   tmp = (unsigned int*)p;    p += (size_t)NB * CAP * 4;          // 16MB
    unsigned char*  tmp2= (unsigned char*)p;   p += (size_t)NB * CAP;              // 4MB
    int*   edge_src = (int*)p;                 p += (size_t)NB * CAP * 4;          // 16MB
    int*   row_beg  = (int*)p;                 p += (size_t)N_NODES * 4;
    int*   row_end  = (int*)p;                 p += (size_t)N_NODES * 4;
    float* norm_src = (float*)p;               p += (size_t)N_NODES * 4;
    float* norm_dst = (float*)p;               p += (size_t)N_NODES * 4;
    int*   cursor_d = (int*)p;                 p += (size_t)NB * 4;
    int*   cursor_s = (int*)p;

    zero_kernel<<<1, 512, 0, stream>>>(cursor_d, cursor_s);
    p2_part<<<NTILE, 512, 0, stream>>>(src, dst, cursor_d, cursor_s, tmp, tmp2);
    p3_build<<<NB, 256, 0, stream>>>(tmp, tmp2, cursor_d, cursor_s, row_beg,
                                     row_end, edge_src, norm_src, norm_dst);
    gemm_kernel<<<(N_NODES + 255) / 256, 256, 0, stream>>>(in_feat, W, bias,
                                                           norm_src, h0b, h8);
    gather_kernel<<<(N_NODES + 3) / 4, 256, 0, stream>>>(row_beg, row_end,
                                                         edge_src, h8, h0b,
                                                         norm_dst, out);
}